// Round 13
// baseline (279.636 us; speedup 1.0000x reference)
//
#include <hip/hip_runtime.h>
#include <hip/hip_bf16.h>
#include <cstdint>
#include <cstddef>

#define N_NODES 100000
#define N_EDGES 1600000
#define EPSV 1e-5f

// ---- workspace layout (bytes) ----
#define OFF_ROWPTR 0            // (N+1) ints -> pad 400384
#define OFF_BC     400384       // 98*16 ints (bucket counts -> partA cursors)
#define OFF_GB     406656       // 99 ints (bucket bases for partB)
#define OFF_BN     407296       // 256 f32
#define OFF_SRC    408320       // E ints
#define OFF_T1B    6808320      // N*128 fp8 (12.8MB) -> t2b (N*64 bf16)
#define OFF_R1B    19608320     // N*128 bf16 (25.6MB) -> r2b
#define OFF_HPRE   45208320     // N*128 bf16 (25.6MB)
#define OFF_TMP    70808320     // E u64 (12.8MB)

#define GEMM_MBLK 3125    // 100000/32 row-tiles
#define HIST_NBLK 625     // 625*256*10 = 1.6M edges
#define NBUK      98      // bucket = dst>>10 (1024 dst rows each)
#define PA_EDGES  4096
#define PA_NBLK   391     // ceil(1.6M/4096)

typedef short v8s __attribute__((ext_vector_type(8)));
typedef float v4f __attribute__((ext_vector_type(4)));
typedef float v2f __attribute__((ext_vector_type(2)));

__device__ __forceinline__ float bf2f(unsigned short u) {
    return __uint_as_float(((unsigned int)u) << 16);
}
__device__ __forceinline__ float bf2f_lo(unsigned int u) {
    return __uint_as_float(u << 16);
}
__device__ __forceinline__ float bf2f_hi(unsigned int u) {
    return __uint_as_float(u & 0xffff0000u);
}
__device__ __forceinline__ unsigned short f2bf(float f) {
    unsigned int u = __float_as_uint(f);
    u += 0x7fffu + ((u >> 16) & 1u);   // round-to-nearest-even
    return (unsigned short)(u >> 16);
}
__device__ __forceinline__ unsigned int pk2(float a, float b) {
    return (unsigned int)f2bf(a) | ((unsigned int)f2bf(b) << 16);
}
__device__ __forceinline__ unsigned char f2fp8(float v) {
    return (unsigned char)(__builtin_amdgcn_cvt_pk_fp8_f32(v, v, 0, 0) & 0xff);
}

#define CVT8ACC(u, A) { \
    v2f f0_ = __builtin_amdgcn_cvt_pk_f32_fp8((int)(u).x, false); \
    v2f f1_ = __builtin_amdgcn_cvt_pk_f32_fp8((int)(u).x, true);  \
    v2f f2_ = __builtin_amdgcn_cvt_pk_f32_fp8((int)(u).y, false); \
    v2f f3_ = __builtin_amdgcn_cvt_pk_f32_fp8((int)(u).y, true);  \
    A[0] += f0_[0]; A[1] += f0_[1]; A[2] += f1_[0]; A[3] += f1_[1]; \
    A[4] += f2_[0]; A[5] += f2_[1]; A[6] += f3_[0]; A[7] += f3_[1]; }

// ---------- tiny scan of 98 bucket counts -> partA cursors + partB bases ----------
__global__ __launch_bounds__(128) void k_scan98(int* __restrict__ bc, int* __restrict__ gbase,
                                                int* __restrict__ rowptr) {
    __shared__ int s[128];
    const int t = threadIdx.x;
    int v = (t < NBUK) ? bc[t * 16] : 0;
    s[t] = v;
    __syncthreads();
    for (int off = 1; off < 128; off <<= 1) {
        int u = (t >= off) ? s[t - off] : 0;
        __syncthreads();
        s[t] += u;
        __syncthreads();
    }
    if (t < NBUK) {
        int ex = s[t] - v;
        bc[t * 16] = ex;
        gbase[t] = ex;
    }
    if (t == 0) {
        gbase[NBUK] = N_EDGES;
        rowptr[N_NODES] = N_EDGES;
    }
}

// ---------- pass A: bucket-partition edges into tmp ----------
__global__ __launch_bounds__(256) void k_partA(const int* __restrict__ esrc, const int* __restrict__ edst,
                                               int* __restrict__ bc,
                                               unsigned long long* __restrict__ tmp) {
    __shared__ int hist[NBUK];
    __shared__ int loffx[NBUK];
    __shared__ int pos[NBUK];
    __shared__ int gbaseL[NBUK];
    __shared__ int sc[128];
    __shared__ unsigned long long stage[PA_EDGES];
    __shared__ unsigned char bkt[PA_EDGES];
    const int t = threadIdx.x;
    const int e0 = blockIdx.x * PA_EDGES;
    const int cnt = min(PA_EDGES, N_EDGES - e0);

    for (int b = t; b < NBUK; b += 256) hist[b] = 0;
    __syncthreads();

    int esr[16], eds[16];
#pragma unroll
    for (int j = 0; j < 16; ++j) {
        int li = t + j * 256;
        if (li < cnt) {
            esr[j] = esrc[e0 + li];
            eds[j] = edst[e0 + li];
            atomicAdd(&hist[eds[j] >> 10], 1);
        } else {
            eds[j] = -1;
        }
    }
    __syncthreads();

    if (t < 128) sc[t] = (t < NBUK) ? hist[t] : 0;
    __syncthreads();
    for (int off = 1; off < 128; off <<= 1) {
        int u = (t >= off && t < 128) ? sc[t - off] : 0;
        __syncthreads();
        if (t < 128) sc[t] += u;
        __syncthreads();
    }
    if (t < NBUK) {
        int ex = sc[t] - hist[t];
        loffx[t] = ex;
        pos[t] = ex;
        gbaseL[t] = atomicAdd(&bc[t * 16], hist[t]);
    }
    __syncthreads();

#pragma unroll
    for (int j = 0; j < 16; ++j) {
        if (eds[j] >= 0) {
            int b = eds[j] >> 10;
            int s = atomicAdd(&pos[b], 1);
            stage[s] = (unsigned long long)(unsigned int)esr[j] |
                       ((unsigned long long)(unsigned int)eds[j] << 32);
            bkt[s] = (unsigned char)b;
        }
    }
    __syncthreads();

    for (int i = t; i < cnt; i += 256) {
        int b = bkt[i];
        tmp[(size_t)gbaseL[b] + (i - loffx[b])] = stage[i];
    }
}

// ---------- pass B: per-bucket LDS histogram + scan -> rowptr + local scatter ----------
__global__ __launch_bounds__(1024) void k_partB(const unsigned long long* __restrict__ tmp,
                                                const int* __restrict__ gbase,
                                                int* __restrict__ rowptr, int* __restrict__ ssrc) {
    __shared__ int cnt[1024];
    __shared__ int cur[1024];
    const int b = blockIdx.x;
    const int t = threadIdx.x;
    const int lo = gbase[b], hi = gbase[b + 1];
    const int nb = b << 10;
    const int rows = min(1024, N_NODES - nb);

    cnt[t] = 0;
    __syncthreads();
    for (int i = lo + t; i < hi; i += 1024) {
        int d = (int)(tmp[i] >> 32);
        atomicAdd(&cnt[d & 1023], 1);
    }
    __syncthreads();
    int v = cnt[t];
    for (int off = 1; off < 1024; off <<= 1) {
        int u = (t >= off) ? cnt[t - off] : 0;
        __syncthreads();
        cnt[t] += u;
        __syncthreads();
    }
    int ex = cnt[t] - v;
    cur[t] = ex;
    if (t < rows) rowptr[nb + t] = lo + ex;
    __syncthreads();
    for (int i = lo + t; i < hi; i += 1024) {
        unsigned long long p = tmp[i];
        int src = (int)(unsigned int)(p & 0xffffffffull);
        int j = ((int)(p >> 32)) & 1023;
        int q = atomicAdd(&cur[j], 1);
        ssrc[lo + q] = src;
    }
}

// ---------- fused: LDS bucket histogram (blocks 0..624) + layer-1 MFMA GEMM ----------
__global__ __launch_bounds__(256) void k_gemm1h(const float* __restrict__ x, const float* __restrict__ Wl,
                                                const float* __restrict__ Wr,
                                                unsigned char* __restrict__ t1b8,
                                                unsigned short* __restrict__ r1b,
                                                const int* __restrict__ edst, int* __restrict__ bc) {
    const int t = threadIdx.x;
    if (blockIdx.x < HIST_NBLK) {
        __shared__ int h[NBUK];
        if (t < NBUK) h[t] = 0;
        __syncthreads();
        int base = blockIdx.x * 2560 + t;
#pragma unroll
        for (int i = 0; i < 10; ++i) atomicAdd(&h[edst[base + i * 256] >> 10], 1);
        __syncthreads();
        if (t < NBUK) atomicAdd(&bc[t * 16], h[t]);
        return;
    }
    __shared__ unsigned short As[32 * 128];
    __shared__ unsigned short Bs[128 * 128];
    const int id = blockIdx.x - HIST_NBLK;
    const int half = id / GEMM_MBLK;
    const int blk = id % GEMM_MBLK;
    const size_t n0 = (size_t)blk * 32;
    const float* __restrict__ W = half ? Wr : Wl;

    {
        const int r = t >> 3, s = t & 7;
        const float* xr = x + (n0 + r) * 128 + s * 16;
        float4 f0 = *(const float4*)(xr + 0);
        float4 f1 = *(const float4*)(xr + 4);
        float4 f2 = *(const float4*)(xr + 8);
        float4 f3 = *(const float4*)(xr + 12);
        uint4 p0 = { pk2(f0.x, f0.y), pk2(f0.z, f0.w), pk2(f1.x, f1.y), pk2(f1.z, f1.w) };
        uint4 p1 = { pk2(f2.x, f2.y), pk2(f2.z, f2.w), pk2(f3.x, f3.y), pk2(f3.z, f3.w) };
        int sw = (r & 7) << 3;
        *(uint4*)&As[(r * 128 + s * 16 + 0) ^ sw] = p0;
        *(uint4*)&As[(r * 128 + s * 16 + 8) ^ sw] = p1;
    }
    {
        const int n = t & 127, kh = t >> 7;
        const float* wc = W + n;
        int sw = (n & 7) << 3;
#pragma unroll
        for (int k = kh * 64; k < kh * 64 + 64; k += 8) {
            float a0 = wc[(k + 0) * 128], a1 = wc[(k + 1) * 128];
            float a2 = wc[(k + 2) * 128], a3 = wc[(k + 3) * 128];
            float a4 = wc[(k + 4) * 128], a5 = wc[(k + 5) * 128];
            float a6 = wc[(k + 6) * 128], a7 = wc[(k + 7) * 128];
            uint4 p = { pk2(a0, a1), pk2(a2, a3), pk2(a4, a5), pk2(a6, a7) };
            *(uint4*)&Bs[(n * 128 + k) ^ sw] = p;
        }
    }
    __syncthreads();

    const int w = t >> 6, l = t & 63;
    const int lr = l & 15, lg = l >> 4;
    v4f acc00 = {0.f, 0.f, 0.f, 0.f}, acc01 = acc00, acc10 = acc00, acc11 = acc00;
    const int swA = (lr & 7) << 3;
    const int nA = w * 32 + lr;
    const int swB = (nA & 7) << 3;
#pragma unroll
    for (int ks = 0; ks < 4; ++ks) {
        const int ka = ks * 32 + lg * 8;
        v8s a0 = *(const v8s*)&As[(lr * 128 + ka) ^ swA];
        v8s a1 = *(const v8s*)&As[((16 + lr) * 128 + ka) ^ swA];
        v8s b0 = *(const v8s*)&Bs[(nA * 128 + ka) ^ swB];
        v8s b1 = *(const v8s*)&Bs[((nA + 16) * 128 + ka) ^ swB];
        acc00 = __builtin_amdgcn_mfma_f32_16x16x32_bf16(a0, b0, acc00, 0, 0, 0);
        acc01 = __builtin_amdgcn_mfma_f32_16x16x32_bf16(a0, b1, acc01, 0, 0, 0);
        acc10 = __builtin_amdgcn_mfma_f32_16x16x32_bf16(a1, b0, acc10, 0, 0, 0);
        acc11 = __builtin_amdgcn_mfma_f32_16x16x32_bf16(a1, b1, acc11, 0, 0, 0);
    }
    const int col0 = w * 32 + lr;
    if (half == 0) {
#pragma unroll
        for (int reg = 0; reg < 4; ++reg) {
            size_t row0 = n0 + lg * 4 + reg;
            size_t row1 = row0 + 16;
            t1b8[row0 * 128 + col0]      = f2fp8(acc00[reg]);
            t1b8[row0 * 128 + col0 + 16] = f2fp8(acc01[reg]);
            t1b8[row1 * 128 + col0]      = f2fp8(acc10[reg]);
            t1b8[row1 * 128 + col0 + 16] = f2fp8(acc11[reg]);
        }
    } else {
#pragma unroll
        for (int reg = 0; reg < 4; ++reg) {
            size_t row0 = n0 + lg * 4 + reg;
            size_t row1 = row0 + 16;
            r1b[row0 * 128 + col0]      = f2bf(acc00[reg]);
            r1b[row0 * 128 + col0 + 16] = f2bf(acc01[reg]);
            r1b[row1 * 128 + col0]      = f2bf(acc10[reg]);
            r1b[row1 * 128 + col0 + 16] = f2bf(acc11[reg]);
        }
    }
}

// ---------- layer 1 aggregate: TWO rows per wave interleaved, 4 edges/wave-load ----------
__global__ __launch_bounds__(256) void k_agg1(const unsigned char* __restrict__ t1b8,
                                              const unsigned short* __restrict__ r1b,
                                              const int* __restrict__ rowptr,
                                              const int* __restrict__ ssrc, const float* __restrict__ b1,
                                              unsigned short* __restrict__ hpreb, float* __restrict__ bn) {
    const int wv = threadIdx.x >> 6;
    const int l  = threadIdx.x & 63;
    const int e  = l >> 4;           // edge slot 0..3
    const int q  = l & 15;           // feature octet
    const int nbase = blockIdx.x * 32;
    float sa[8], sq[8];
#pragma unroll
    for (int j = 0; j < 8; ++j) { sa[j] = 0.f; sq[j] = 0.f; }

    for (int k = 0; k < 4; ++k) {
        const int nA = nbase + wv * 8 + k;
        const int nB = nA + 4;
        const int loA = rowptr[nA], hiA = rowptr[nA + 1];
        const int loB = rowptr[nB], hiB = rowptr[nB + 1];
        float accA[8], accB[8];
#pragma unroll
        for (int j = 0; j < 8; ++j) { accA[j] = 0.f; accB[j] = 0.f; }
        int iA = loA, iB = loB;
        // dual-row main loop: up to 8 wide loads in flight
        while (true) {
            bool dA = (iA + 16 <= hiA), dB = (iB + 16 <= hiB);
            if (!(dA || dB)) break;
            uint2 uA0, uA1, uA2, uA3, uB0, uB1, uB2, uB3;
            if (dA) {
                int s0 = ssrc[iA + e], s1 = ssrc[iA + 4 + e], s2 = ssrc[iA + 8 + e], s3 = ssrc[iA + 12 + e];
                uA0 = *(const uint2*)&t1b8[(size_t)s0 * 128 + q * 8];
                uA1 = *(const uint2*)&t1b8[(size_t)s1 * 128 + q * 8];
                uA2 = *(const uint2*)&t1b8[(size_t)s2 * 128 + q * 8];
                uA3 = *(const uint2*)&t1b8[(size_t)s3 * 128 + q * 8];
            }
            if (dB) {
                int s0 = ssrc[iB + e], s1 = ssrc[iB + 4 + e], s2 = ssrc[iB + 8 + e], s3 = ssrc[iB + 12 + e];
                uB0 = *(const uint2*)&t1b8[(size_t)s0 * 128 + q * 8];
                uB1 = *(const uint2*)&t1b8[(size_t)s1 * 128 + q * 8];
                uB2 = *(const uint2*)&t1b8[(size_t)s2 * 128 + q * 8];
                uB3 = *(const uint2*)&t1b8[(size_t)s3 * 128 + q * 8];
            }
            if (dA) {
                CVT8ACC(uA0, accA); CVT8ACC(uA1, accA); CVT8ACC(uA2, accA); CVT8ACC(uA3, accA);
                iA += 16;
            }
            if (dB) {
                CVT8ACC(uB0, accB); CVT8ACC(uB1, accB); CVT8ACC(uB2, accB); CVT8ACC(uB3, accB);
                iB += 16;
            }
        }
        // tapered tails (8 / 4 / masked), A and B interleaved for overlap
        {
            bool a8 = (iA + 8 <= hiA), b8 = (iB + 8 <= hiB);
            uint2 uA0, uA1, uB0, uB1;
            if (a8) {
                int s0 = ssrc[iA + e], s1 = ssrc[iA + 4 + e];
                uA0 = *(const uint2*)&t1b8[(size_t)s0 * 128 + q * 8];
                uA1 = *(const uint2*)&t1b8[(size_t)s1 * 128 + q * 8];
            }
            if (b8) {
                int s0 = ssrc[iB + e], s1 = ssrc[iB + 4 + e];
                uB0 = *(const uint2*)&t1b8[(size_t)s0 * 128 + q * 8];
                uB1 = *(const uint2*)&t1b8[(size_t)s1 * 128 + q * 8];
            }
            if (a8) { CVT8ACC(uA0, accA); CVT8ACC(uA1, accA); iA += 8; }
            if (b8) { CVT8ACC(uB0, accB); CVT8ACC(uB1, accB); iB += 8; }
        }
        {
            bool a4 = (iA + 4 <= hiA), b4 = (iB + 4 <= hiB);
            uint2 uA0, uB0;
            if (a4) uA0 = *(const uint2*)&t1b8[(size_t)ssrc[iA + e] * 128 + q * 8];
            if (b4) uB0 = *(const uint2*)&t1b8[(size_t)ssrc[iB + e] * 128 + q * 8];
            if (a4) { CVT8ACC(uA0, accA); iA += 4; }
            if (b4) { CVT8ACC(uB0, accB); iB += 4; }
        }
        {
            bool am = (e < hiA - iA), bm = (e < hiB - iB);
            uint2 uA0, uB0;
            if (am) uA0 = *(const uint2*)&t1b8[(size_t)ssrc[iA + e] * 128 + q * 8];
            if (bm) uB0 = *(const uint2*)&t1b8[(size_t)ssrc[iB + e] * 128 + q * 8];
            if (am) CVT8ACC(uA0, accA);
            if (bm) CVT8ACC(uB0, accB);
        }
        // reduce across edge slots
#pragma unroll
        for (int j = 0; j < 8; ++j) {
            accA[j] += __shfl_xor(accA[j], 16);
            accA[j] += __shfl_xor(accA[j], 32);
            accB[j] += __shfl_xor(accB[j], 16);
            accB[j] += __shfl_xor(accB[j], 32);
        }
        if (e == 0) {
            float4 bA = *(const float4*)&b1[q * 8];
            float4 bB = *(const float4*)&b1[q * 8 + 4];
            {
                float c = (float)(hiA - loA);
                if (c < 1.f) c = 1.f;
                float inv = 1.0f / c;
                uint4 ur = *(const uint4*)&r1b[(size_t)nA * 128 + q * 8];
                float v0 = accA[0] * inv + bA.x + bf2f_lo(ur.x);
                float v1 = accA[1] * inv + bA.y + bf2f_hi(ur.x);
                float v2 = accA[2] * inv + bA.z + bf2f_lo(ur.y);
                float v3 = accA[3] * inv + bA.w + bf2f_hi(ur.y);
                float v4 = accA[4] * inv + bB.x + bf2f_lo(ur.z);
                float v5 = accA[5] * inv + bB.y + bf2f_hi(ur.z);
                float v6 = accA[6] * inv + bB.z + bf2f_lo(ur.w);
                float v7 = accA[7] * inv + bB.w + bf2f_hi(ur.w);
                uint4 pw = { pk2(v0, v1), pk2(v2, v3), pk2(v4, v5), pk2(v6, v7) };
                *(uint4*)&hpreb[(size_t)nA * 128 + q * 8] = pw;
                sa[0] += v0; sa[1] += v1; sa[2] += v2; sa[3] += v3;
                sa[4] += v4; sa[5] += v5; sa[6] += v6; sa[7] += v7;
                sq[0] += v0 * v0; sq[1] += v1 * v1; sq[2] += v2 * v2; sq[3] += v3 * v3;
                sq[4] += v4 * v4; sq[5] += v5 * v5; sq[6] += v6 * v6; sq[7] += v7 * v7;
            }
            {
                float c = (float)(hiB - loB);
                if (c < 1.f) c = 1.f;
                float inv = 1.0f / c;
                uint4 ur = *(const uint4*)&r1b[(size_t)nB * 128 + q * 8];
                float v0 = accB[0] * inv + bA.x + bf2f_lo(ur.x);
                float v1 = accB[1] * inv + bA.y + bf2f_hi(ur.x);
                float v2 = accB[2] * inv + bA.z + bf2f_lo(ur.y);
                float v3 = accB[3] * inv + bA.w + bf2f_hi(ur.y);
                float v4 = accB[4] * inv + bB.x + bf2f_lo(ur.z);
                float v5 = accB[5] * inv + bB.y + bf2f_hi(ur.z);
                float v6 = accB[6] * inv + bB.z + bf2f_lo(ur.w);
                float v7 = accB[7] * inv + bB.w + bf2f_hi(ur.w);
                uint4 pw = { pk2(v0, v1), pk2(v2, v3), pk2(v4, v5), pk2(v6, v7) };
                *(uint4*)&hpreb[(size_t)nB * 128 + q * 8] = pw;
                sa[0] += v0; sa[1] += v1; sa[2] += v2; sa[3] += v3;
                sa[4] += v4; sa[5] += v5; sa[6] += v6; sa[7] += v7;
                sq[0] += v0 * v0; sq[1] += v1 * v1; sq[2] += v2 * v2; sq[3] += v3 * v3;
                sq[4] += v4 * v4; sq[5] += v5 * v5; sq[6] += v6 * v6; sq[7] += v7 * v7;
            }
        }
    }

    __shared__ float red[2][4][128];
    if (e == 0) {
#pragma unroll
        for (int j = 0; j < 8; ++j) {
            red[0][wv][q * 8 + j] = sa[j];
            red[1][wv][q * 8 + j] = sq[j];
        }
    }
    __syncthreads();
    int t = threadIdx.x;
    if (t < 128) {
        atomicAdd(&bn[t], red[0][0][t] + red[0][1][t] + red[0][2][t] + red[0][3][t]);
    } else {
        int f = t - 128;
        atomicAdd(&bn[128 + f], red[1][0][f] + red[1][1][f] + red[1][2][f] + red[1][3][f]);
    }
}

// ---------- layer 2 MFMA GEMM with fused BN-finalize + BN+ReLU ----------
__global__ __launch_bounds__(256) void k_gemm2m(const unsigned short* __restrict__ hpreb,
                                                const float* __restrict__ bnp,
                                                const float* __restrict__ gamma, const float* __restrict__ beta,
                                                const float* __restrict__ Wl, const float* __restrict__ Wr,
                                                unsigned short* __restrict__ t2b,
                                                unsigned short* __restrict__ r2b) {
    __shared__ unsigned short As[32 * 128];
    __shared__ unsigned short Bs[128 * 128];
    __shared__ float scs[128], shs[128];
    const int t = threadIdx.x;
    const size_t n0 = (size_t)blockIdx.x * 32;

    if (t < 128) {
        float mean = bnp[t] * (1.0f / N_NODES);
        float var  = bnp[128 + t] * (1.0f / N_NODES) - mean * mean;
        float sc = gamma[t] * rsqrtf(var + EPSV);
        scs[t] = sc;
        shs[t] = beta[t] - mean * sc;
    }
    __syncthreads();

    {
        const int r = t >> 3, s = t & 7;
        const unsigned short* hr = hpreb + (n0 + r) * 128 + s * 16;
        uint4 h0 = *(const uint4*)(hr + 0);
        uint4 h1 = *(const uint4*)(hr + 8);
        unsigned int hv[8] = { h0.x, h0.y, h0.z, h0.w, h1.x, h1.y, h1.z, h1.w };
        float v[16];
#pragma unroll
        for (int j = 0; j < 8; ++j) {
            v[2 * j]     = bf2f_lo(hv[j]);
            v[2 * j + 1] = bf2f_hi(hv[j]);
        }
#pragma unroll
        for (int j = 0; j < 16; ++j) {
            int f = s * 16 + j;
            float val = fmaf(scs[f], v[j], shs[f]);
            v[j] = val > 0.f ? val : 0.f;
        }
        uint4 p0 = { pk2(v[0], v[1]), pk2(v[2], v[3]), pk2(v[4], v[5]), pk2(v[6], v[7]) };
        uint4 p1 = { pk2(v[8], v[9]), pk2(v[10], v[11]), pk2(v[12], v[13]), pk2(v[14], v[15]) };
        int sw = (r & 7) << 3;
        *(uint4*)&As[(r * 128 + s * 16 + 0) ^ sw] = p0;
        *(uint4*)&As[(r * 128 + s * 16 + 8) ^ sw] = p1;
    }
    {
        const int n = t & 127, kh = t >> 7;
        const float* wc = (n < 64) ? (Wl + n) : (Wr + (n - 64));
        int sw = (n & 7) << 3;
#pragma unroll
        for (int k = kh * 64; k < kh * 64 + 64; k += 8) {
            float a0 = wc[(k + 0) * 64], a1 = wc[(k + 1) * 64];
            float a2 = wc[(k + 2) * 64], a3 = wc[(k + 3) * 64];
            float a4 = wc[(k + 4) * 64], a5 = wc[(k + 5) * 64];
            float a6 = wc[(k + 6) * 64], a7 = wc[(k + 7) * 64];
            uint4 p = { pk2(a0, a1), pk2(a2, a3), pk2(a4, a5), pk2(a6, a7) };
            *(uint4*)&Bs[(n * 128 + k) ^ sw] = p;
        }
    }
    __syncthreads();

    const int w = t >> 6, l = t & 63;
    const int lr = l & 15, lg = l >> 4;
    v4f acc00 = {0.f, 0.f, 0.f, 0.f}, acc01 = acc00, acc10 = acc00, acc11 = acc00;
    const int swA = (lr & 7) << 3;
    const int nA = w * 32 + lr;
    const int swB = (nA & 7) << 3;
#pragma unroll
    for (int ks = 0; ks < 4; ++ks) {
        const int ka = ks * 32 + lg * 8;
        v8s a0 = *(const v8s*)&As[(lr * 128 + ka) ^ swA];
        v8s a1 = *(const v8s*)&As[((16 + lr) * 128 + ka) ^ swA];
        v8s b0 = *(const v8s*)&Bs[(nA * 128 + ka) ^ swB];
        v8s b1 = *(const v8s*)&Bs[((nA + 16) * 128 + ka) ^ swB];
        acc00 = __builtin_amdgcn_mfma_f32_16x16x32_bf16(a0, b0, acc00, 0, 0, 0);
        acc01 = __builtin_amdgcn_mfma_f32_16x16x32_bf16(a0, b1, acc01, 0, 0, 0);
        acc10 = __builtin_amdgcn_mfma_f32_16x16x32_bf16(a1, b0, acc10, 0, 0, 0);
        acc11 = __builtin_amdgcn_mfma_f32_16x16x32_bf16(a1, b1, acc11, 0, 0, 0);
    }
    unsigned short* __restrict__ ob = (w < 2) ? t2b : r2b;
    const int col0 = (w < 2) ? (w * 32 + lr) : ((w - 2) * 32 + lr);
#pragma unroll
    for (int reg = 0; reg < 4; ++reg) {
        size_t row0 = n0 + lg * 4 + reg;
        size_t row1 = row0 + 16;
        ob[row0 * 64 + col0]      = f2bf(acc00[reg]);
        ob[row0 * 64 + col0 + 16] = f2bf(acc01[reg]);
        ob[row1 * 64 + col0]      = f2bf(acc10[reg]);
        ob[row1 * 64 + col0 + 16] = f2bf(acc11[reg]);
    }
}

// ---------- layer 2 aggregate: TWO rows per wave interleaved ----------
__global__ __launch_bounds__(256) void k_agg2(const unsigned short* __restrict__ t2b,
                                              const unsigned short* __restrict__ r2b,
                                              const int* __restrict__ rowptr,
                                              const int* __restrict__ ssrc, const float* __restrict__ b2,
                                              float* __restrict__ out) {
    const int wv = threadIdx.x >> 6;
    const int l  = threadIdx.x & 63;
    const int e  = l >> 4;
    const int q  = l & 15;
    const int nbase = blockIdx.x * 16;

#define BACC(u, A) { A[0] += bf2f_lo((u).x); A[1] += bf2f_hi((u).x); A[2] += bf2f_lo((u).y); A[3] += bf2f_hi((u).y); }

    for (int k = 0; k < 2; ++k) {
        const int nA = nbase + wv * 4 + k;
        const int nB = nA + 2;
        const int loA = rowptr[nA], hiA = rowptr[nA + 1];
        const int loB = rowptr[nB], hiB = rowptr[nB + 1];
        float accA[4] = {0.f, 0.f, 0.f, 0.f}, accB[4] = {0.f, 0.f, 0.f, 0.f};
        int iA = loA, iB = loB;
        while (true) {
            bool dA = (iA + 16 <= hiA), dB = (iB + 16 <= hiB);
            if (!(dA || dB)) break;
            uint2 uA0, uA1, uA2, uA3, uB0, uB1, uB2, uB3;
            if (dA) {
                int s0 = ssrc[iA + e], s1 = ssrc[iA + 4 + e], s2 = ssrc[iA + 8 + e], s3 = ssrc[iA + 12 + e];
                uA0 = *(const uint2*)&t2b[(size_t)s0 * 64 + q * 4];
                uA1 = *(const uint2*)&t2b[(size_t)s1 * 64 + q * 4];
                uA2 = *(const uint2*)&t2b[(size_t)s2 * 64 + q * 4];
                uA3 = *(const uint2*)&t2b[(size_t)s3 * 64 + q * 4];
            }
            if (dB) {
                int s0 = ssrc[iB + e], s1 = ssrc[iB + 4 + e], s2 = ssrc[iB + 8 + e], s3 = ssrc[iB + 12 + e];
                uB0 = *(const uint2*)&t2b[(size_t)s0 * 64 + q * 4];
                uB1 = *(const uint2*)&t2b[(size_t)s1 * 64 + q * 4];
                uB2 = *(const uint2*)&t2b[(size_t)s2 * 64 + q * 4];
                uB3 = *(const uint2*)&t2b[(size_t)s3 * 64 + q * 4];
            }
            if (dA) { BACC(uA0, accA); BACC(uA1, accA); BACC(uA2, accA); BACC(uA3, accA); iA += 16; }
            if (dB) { BACC(uB0, accB); BACC(uB1, accB); BACC(uB2, accB); BACC(uB3, accB); iB += 16; }
        }
        {
            bool a8 = (iA + 8 <= hiA), b8 = (iB + 8 <= hiB);
            uint2 uA0, uA1, uB0, uB1;
            if (a8) {
                int s0 = ssrc[iA + e], s1 = ssrc[iA + 4 + e];
                uA0 = *(const uint2*)&t2b[(size_t)s0 * 64 + q * 4];
                uA1 = *(const uint2*)&t2b[(size_t)s1 * 64 + q * 4];
            }
            if (b8) {
                int s0 = ssrc[iB + e], s1 = ssrc[iB + 4 + e];
                uB0 = *(const uint2*)&t2b[(size_t)s0 * 64 + q * 4];
                uB1 = *(const uint2*)&t2b[(size_t)s1 * 64 + q * 4];
            }
            if (a8) { BACC(uA0, accA); BACC(uA1, accA); iA += 8; }
            if (b8) { BACC(uB0, accB); BACC(uB1, accB); iB += 8; }
        }
        {
            bool a4 = (iA + 4 <= hiA), b4 = (iB + 4 <= hiB);
            uint2 uA0, uB0;
            if (a4) uA0 = *(const uint2*)&t2b[(size_t)ssrc[iA + e] * 64 + q * 4];
            if (b4) uB0 = *(const uint2*)&t2b[(size_t)ssrc[iB + e] * 64 + q * 4];
            if (a4) { BACC(uA0, accA); iA += 4; }
            if (b4) { BACC(uB0, accB); iB += 4; }
        }
        {
            bool am = (e < hiA - iA), bm = (e < hiB - iB);
            uint2 uA0, uB0;
            if (am) uA0 = *(const uint2*)&t2b[(size_t)ssrc[iA + e] * 64 + q * 4];
            if (bm) uB0 = *(const uint2*)&t2b[(size_t)ssrc[iB + e] * 64 + q * 4];
            if (am) BACC(uA0, accA);
            if (bm) BACC(uB0, accB);
        }
#pragma unroll
        for (int j = 0; j < 4; ++j) {
            accA[j] += __shfl_xor(accA[j], 16);
            accA[j] += __shfl_xor(accA[j], 32);
            accB[j] += __shfl_xor(accB[j], 16);
            accB[j] += __shfl_xor(accB[j], 32);
        }
        if (e == 0) {
            float4 bias = *(const float4*)&b2[q * 4];
            {
                float c = (float)(hiA - loA);
                if (c < 1.f) c = 1.f;
                float inv = 1.0f / c;
                uint2 ur = *(const uint2*)&r2b[(size_t)nA * 64 + q * 4];
                float4 o = { accA[0] * inv + bias.x + bf2f_lo(ur.x),
                             accA[1] * inv + bias.y + bf2f_hi(ur.x),
                             accA[2] * inv + bias.z + bf2f_lo(ur.y),
                             accA[3] * inv + bias.w + bf2f_hi(ur.y) };
                *(float4*)&out[(size_t)nA * 64 + q * 4] = o;
            }
            {
                float c = (float)(hiB - loB);
                if (c < 1.f) c = 1.f;
                float inv = 1.0f / c;
                uint2 ur = *(const uint2*)&r2b[(size_t)nB * 64 + q * 4];
                float4 o = { accB[0] * inv + bias.x + bf2f_lo(ur.x),
                             accB[1] * inv + bias.y + bf2f_hi(ur.x),
                             accB[2] * inv + bias.z + bf2f_lo(ur.y),
                             accB[3] * inv + bias.w + bf2f_hi(ur.y) };
                *(float4*)&out[(size_t)nB * 64 + q * 4] = o;
            }
        }
    }
#undef BACC
}

extern "C" void kernel_launch(void* const* d_in, const int* in_sizes, int n_in,
                              void* d_out, int out_size, void* d_ws, size_t ws_size,
                              hipStream_t stream) {
    const float* x      = (const float*)d_in[0];
    const int*   ei     = (const int*)d_in[1];
    const float* Wl1    = (const float*)d_in[2];
    const float* b1     = (const float*)d_in[3];
    const float* Wr1    = (const float*)d_in[4];
    const float* gamma1 = (const float*)d_in[5];
    const float* beta1  = (const float*)d_in[6];
    const float* Wl2    = (const float*)d_in[7];
    const float* b2     = (const float*)d_in[8];
    const float* Wr2    = (const float*)d_in[9];
    float* out = (float*)d_out;

    char* ws = (char*)d_ws;
    int*                rowptr = (int*)(ws + OFF_ROWPTR);
    int*                bc     = (int*)(ws + OFF_BC);
    int*                gbase  = (int*)(ws + OFF_GB);
    float*              bn     = (float*)(ws + OFF_BN);
    int*                ssrc   = (int*)(ws + OFF_SRC);
    unsigned char*      t1b8   = (unsigned char*)(ws + OFF_T1B);
    unsigned short*     r1b    = (unsigned short*)(ws + OFF_R1B);
    unsigned short*     hpreb  = (unsigned short*)(ws + OFF_HPRE);
    unsigned short*     t2b    = (unsigned short*)(ws + OFF_T1B);
    unsigned short*     r2b    = r1b;
    unsigned long long* tmp    = (unsigned long long*)(ws + OFF_TMP);

    const int* esrc = ei;
    const int* edst = ei + N_EDGES;

    hipMemsetAsync(bc, 0, NBUK * 16 * sizeof(int), stream);
    hipMemsetAsync(bn, 0, 256 * sizeof(float), stream);

    k_gemm1h<<<HIST_NBLK + 2 * GEMM_MBLK, 256, 0, stream>>>(x, Wl1, Wr1, t1b8, r1b, edst, bc);
    k_scan98<<<1, 128, 0, stream>>>(bc, gbase, rowptr);
    k_partA<<<PA_NBLK, 256, 0, stream>>>(esrc, edst, bc, tmp);
    k_partB<<<NBUK, 1024, 0, stream>>>(tmp, gbase, rowptr, ssrc);

    k_agg1<<<N_NODES / 32, 256, 0, stream>>>(t1b8, r1b, rowptr, ssrc, b1, hpreb, bn);
    k_gemm2m<<<GEMM_MBLK, 256, 0, stream>>>(hpreb, bn, gamma1, beta1, Wl2, Wr2, t2b, r2b);
    k_agg2<<<N_NODES / 16, 256, 0, stream>>>(t2b, r2b, rowptr, ssrc, b2, out);
}

// Round 14
// 275.179 us; speedup vs baseline: 1.0162x; 1.0162x over previous
//
#include <hip/hip_runtime.h>
#include <hip/hip_bf16.h>
#include <cstdint>
#include <cstddef>

#define N_NODES 100000
#define N_EDGES 1600000
#define EPSV 1e-5f

// ---- workspace layout (bytes) ----
#define OFF_ROWPTR 0            // (N+1) ints -> pad 400384
#define OFF_BC     400384       // 98*16 ints (bucket counts -> partA cursors)
#define OFF_GB     406656       // 99 ints (bucket bases for partB)
#define OFF_BN     407296       // 256 f32 (raw sum|sumsq)
#define OFF_SRC    408320       // E ints
#define OFF_T1B    6808320      // N*128 fp8 (12.8MB) -> t2b (N*64 bf16)
#define OFF_R1B    19608320     // N*128 bf16 (25.6MB) -> r2b
#define OFF_HPRE   45208320     // N*128 bf16 (25.6MB)
#define OFF_TMP    70808320     // E u64 (12.8MB)

#define GEMM_MBLK 3125    // 100000/32 row-tiles
#define HIST_NBLK 625     // 625*256*10 = 1.6M edges
#define NBUK      98      // bucket = dst>>10 (1024 dst rows each)
#define PA_EDGES  4096
#define PA_NBLK   391     // ceil(1.6M/4096)

typedef short v8s __attribute__((ext_vector_type(8)));
typedef float v4f __attribute__((ext_vector_type(4)));
typedef float v2f __attribute__((ext_vector_type(2)));

__device__ __forceinline__ float bf2f_lo(unsigned int u) {
    return __uint_as_float(u << 16);
}
__device__ __forceinline__ float bf2f_hi(unsigned int u) {
    return __uint_as_float(u & 0xffff0000u);
}
__device__ __forceinline__ unsigned short f2bf(float f) {
    unsigned int u = __float_as_uint(f);
    u += 0x7fffu + ((u >> 16) & 1u);   // round-to-nearest-even
    return (unsigned short)(u >> 16);
}
__device__ __forceinline__ unsigned int pk2(float a, float b) {
    return (unsigned int)f2bf(a) | ((unsigned int)f2bf(b) << 16);
}
__device__ __forceinline__ unsigned char f2fp8(float v) {
    return (unsigned char)(__builtin_amdgcn_cvt_pk_fp8_f32(v, v, 0, 0) & 0xff);
}

// ---------- tiny scan of 98 bucket counts -> partA cursors + partB bases ----------
__global__ __launch_bounds__(128) void k_scan98(int* __restrict__ bc, int* __restrict__ gbase,
                                                int* __restrict__ rowptr) {
    __shared__ int s[128];
    const int t = threadIdx.x;
    int v = (t < NBUK) ? bc[t * 16] : 0;
    s[t] = v;
    __syncthreads();
    for (int off = 1; off < 128; off <<= 1) {
        int u = (t >= off) ? s[t - off] : 0;
        __syncthreads();
        s[t] += u;
        __syncthreads();
    }
    if (t < NBUK) {
        int ex = s[t] - v;
        bc[t * 16] = ex;
        gbase[t] = ex;
    }
    if (t == 0) {
        gbase[NBUK] = N_EDGES;
        rowptr[N_NODES] = N_EDGES;
    }
}

// ---------- pass A: bucket-partition edges into tmp ----------
__global__ __launch_bounds__(256) void k_partA(const int* __restrict__ esrc, const int* __restrict__ edst,
                                               int* __restrict__ bc,
                                               unsigned long long* __restrict__ tmp) {
    __shared__ int hist[NBUK];
    __shared__ int loffx[NBUK];
    __shared__ int pos[NBUK];
    __shared__ int gbaseL[NBUK];
    __shared__ int sc[128];
    __shared__ unsigned long long stage[PA_EDGES];
    __shared__ unsigned char bkt[PA_EDGES];
    const int t = threadIdx.x;
    const int e0 = blockIdx.x * PA_EDGES;
    const int cnt = min(PA_EDGES, N_EDGES - e0);

    for (int b = t; b < NBUK; b += 256) hist[b] = 0;
    __syncthreads();

    int esr[16], eds[16];
#pragma unroll
    for (int j = 0; j < 16; ++j) {
        int li = t + j * 256;
        if (li < cnt) {
            esr[j] = esrc[e0 + li];
            eds[j] = edst[e0 + li];
            atomicAdd(&hist[eds[j] >> 10], 1);
        } else {
            eds[j] = -1;
        }
    }
    __syncthreads();

    if (t < 128) sc[t] = (t < NBUK) ? hist[t] : 0;
    __syncthreads();
    for (int off = 1; off < 128; off <<= 1) {
        int u = (t >= off && t < 128) ? sc[t - off] : 0;
        __syncthreads();
        if (t < 128) sc[t] += u;
        __syncthreads();
    }
    if (t < NBUK) {
        int ex = sc[t] - hist[t];
        loffx[t] = ex;
        pos[t] = ex;
        gbaseL[t] = atomicAdd(&bc[t * 16], hist[t]);
    }
    __syncthreads();

#pragma unroll
    for (int j = 0; j < 16; ++j) {
        if (eds[j] >= 0) {
            int b = eds[j] >> 10;
            int s = atomicAdd(&pos[b], 1);
            stage[s] = (unsigned long long)(unsigned int)esr[j] |
                       ((unsigned long long)(unsigned int)eds[j] << 32);
            bkt[s] = (unsigned char)b;
        }
    }
    __syncthreads();

    for (int i = t; i < cnt; i += 256) {
        int b = bkt[i];
        tmp[(size_t)gbaseL[b] + (i - loffx[b])] = stage[i];
    }
}

// ---------- pass B: per-bucket LDS histogram + scan -> rowptr + local scatter ----------
__global__ __launch_bounds__(1024) void k_partB(const unsigned long long* __restrict__ tmp,
                                                const int* __restrict__ gbase,
                                                int* __restrict__ rowptr, int* __restrict__ ssrc) {
    __shared__ int cnt[1024];
    __shared__ int cur[1024];
    const int b = blockIdx.x;
    const int t = threadIdx.x;
    const int lo = gbase[b], hi = gbase[b + 1];
    const int nb = b << 10;
    const int rows = min(1024, N_NODES - nb);

    cnt[t] = 0;
    __syncthreads();
    for (int i = lo + t; i < hi; i += 1024) {
        int d = (int)(tmp[i] >> 32);
        atomicAdd(&cnt[d & 1023], 1);
    }
    __syncthreads();
    int v = cnt[t];
    for (int off = 1; off < 1024; off <<= 1) {
        int u = (t >= off) ? cnt[t - off] : 0;
        __syncthreads();
        cnt[t] += u;
        __syncthreads();
    }
    int ex = cnt[t] - v;
    cur[t] = ex;
    if (t < rows) rowptr[nb + t] = lo + ex;
    __syncthreads();
    for (int i = lo + t; i < hi; i += 1024) {
        unsigned long long p = tmp[i];
        int src = (int)(unsigned int)(p & 0xffffffffull);
        int j = ((int)(p >> 32)) & 1023;
        int q = atomicAdd(&cur[j], 1);
        ssrc[lo + q] = src;
    }
}

// ---------- fused: LDS bucket histogram (blocks 0..624) + layer-1 MFMA GEMM ----------
__global__ __launch_bounds__(256) void k_gemm1h(const float* __restrict__ x, const float* __restrict__ Wl,
                                                const float* __restrict__ Wr,
                                                unsigned char* __restrict__ t1b8,
                                                unsigned short* __restrict__ r1b,
                                                const int* __restrict__ edst, int* __restrict__ bc) {
    const int t = threadIdx.x;
    if (blockIdx.x < HIST_NBLK) {
        __shared__ int h[NBUK];
        if (t < NBUK) h[t] = 0;
        __syncthreads();
        int base = blockIdx.x * 2560 + t;
#pragma unroll
        for (int i = 0; i < 10; ++i) atomicAdd(&h[edst[base + i * 256] >> 10], 1);
        __syncthreads();
        if (t < NBUK) atomicAdd(&bc[t * 16], h[t]);
        return;
    }
    __shared__ unsigned short As[32 * 128];
    __shared__ unsigned short Bs[128 * 128];
    const int id = blockIdx.x - HIST_NBLK;
    const int half = id / GEMM_MBLK;
    const int blk = id % GEMM_MBLK;
    const size_t n0 = (size_t)blk * 32;
    const float* __restrict__ W = half ? Wr : Wl;

    {
        const int r = t >> 3, s = t & 7;
        const float* xr = x + (n0 + r) * 128 + s * 16;
        float4 f0 = *(const float4*)(xr + 0);
        float4 f1 = *(const float4*)(xr + 4);
        float4 f2 = *(const float4*)(xr + 8);
        float4 f3 = *(const float4*)(xr + 12);
        uint4 p0 = { pk2(f0.x, f0.y), pk2(f0.z, f0.w), pk2(f1.x, f1.y), pk2(f1.z, f1.w) };
        uint4 p1 = { pk2(f2.x, f2.y), pk2(f2.z, f2.w), pk2(f3.x, f3.y), pk2(f3.z, f3.w) };
        int sw = (r & 7) << 3;
        *(uint4*)&As[(r * 128 + s * 16 + 0) ^ sw] = p0;
        *(uint4*)&As[(r * 128 + s * 16 + 8) ^ sw] = p1;
    }
    {
        const int n = t & 127, kh = t >> 7;
        const float* wc = W + n;
        int sw = (n & 7) << 3;
#pragma unroll
        for (int k = kh * 64; k < kh * 64 + 64; k += 8) {
            float a0 = wc[(k + 0) * 128], a1 = wc[(k + 1) * 128];
            float a2 = wc[(k + 2) * 128], a3 = wc[(k + 3) * 128];
            float a4 = wc[(k + 4) * 128], a5 = wc[(k + 5) * 128];
            float a6 = wc[(k + 6) * 128], a7 = wc[(k + 7) * 128];
            uint4 p = { pk2(a0, a1), pk2(a2, a3), pk2(a4, a5), pk2(a6, a7) };
            *(uint4*)&Bs[(n * 128 + k) ^ sw] = p;
        }
    }
    __syncthreads();

    const int w = t >> 6, l = t & 63;
    const int lr = l & 15, lg = l >> 4;
    v4f acc00 = {0.f, 0.f, 0.f, 0.f}, acc01 = acc00, acc10 = acc00, acc11 = acc00;
    const int swA = (lr & 7) << 3;
    const int nA = w * 32 + lr;
    const int swB = (nA & 7) << 3;
#pragma unroll
    for (int ks = 0; ks < 4; ++ks) {
        const int ka = ks * 32 + lg * 8;
        v8s a0 = *(const v8s*)&As[(lr * 128 + ka) ^ swA];
        v8s a1 = *(const v8s*)&As[((16 + lr) * 128 + ka) ^ swA];
        v8s b0 = *(const v8s*)&Bs[(nA * 128 + ka) ^ swB];
        v8s b1 = *(const v8s*)&Bs[((nA + 16) * 128 + ka) ^ swB];
        acc00 = __builtin_amdgcn_mfma_f32_16x16x32_bf16(a0, b0, acc00, 0, 0, 0);
        acc01 = __builtin_amdgcn_mfma_f32_16x16x32_bf16(a0, b1, acc01, 0, 0, 0);
        acc10 = __builtin_amdgcn_mfma_f32_16x16x32_bf16(a1, b0, acc10, 0, 0, 0);
        acc11 = __builtin_amdgcn_mfma_f32_16x16x32_bf16(a1, b1, acc11, 0, 0, 0);
    }
    const int col0 = w * 32 + lr;
    if (half == 0) {
#pragma unroll
        for (int reg = 0; reg < 4; ++reg) {
            size_t row0 = n0 + lg * 4 + reg;
            size_t row1 = row0 + 16;
            t1b8[row0 * 128 + col0]      = f2fp8(acc00[reg]);
            t1b8[row0 * 128 + col0 + 16] = f2fp8(acc01[reg]);
            t1b8[row1 * 128 + col0]      = f2fp8(acc10[reg]);
            t1b8[row1 * 128 + col0 + 16] = f2fp8(acc11[reg]);
        }
    } else {
#pragma unroll
        for (int reg = 0; reg < 4; ++reg) {
            size_t row0 = n0 + lg * 4 + reg;
            size_t row1 = row0 + 16;
            r1b[row0 * 128 + col0]      = f2bf(acc00[reg]);
            r1b[row0 * 128 + col0 + 16] = f2bf(acc01[reg]);
            r1b[row1 * 128 + col0]      = f2bf(acc10[reg]);
            r1b[row1 * 128 + col0 + 16] = f2bf(acc11[reg]);
        }
    }
}

// ---------- layer 1 aggregate: 4 edges per wave-load (8 fp8/lane, 16 lanes/row) ----------
__global__ __launch_bounds__(256) void k_agg1(const unsigned char* __restrict__ t1b8,
                                              const unsigned short* __restrict__ r1b,
                                              const int* __restrict__ rowptr,
                                              const int* __restrict__ ssrc, const float* __restrict__ b1,
                                              unsigned short* __restrict__ hpreb, float* __restrict__ bn) {
    const int wv = threadIdx.x >> 6;
    const int l  = threadIdx.x & 63;
    const int e  = l >> 4;           // edge slot 0..3
    const int q  = l & 15;           // feature octet
    const int nbase = blockIdx.x * 32;
    float sa[8], sq[8];
#pragma unroll
    for (int j = 0; j < 8; ++j) { sa[j] = 0.f; sq[j] = 0.f; }

    for (int r = wv; r < 32; r += 4) {
        const int n = nbase + r;
        const int lo = rowptr[n], hi = rowptr[n + 1];
        float acc[8];
#pragma unroll
        for (int j = 0; j < 8; ++j) acc[j] = 0.f;
        int i = lo;
        for (; i + 16 <= hi; i += 16) {
            int s0 = ssrc[i + e], s1 = ssrc[i + 4 + e], s2 = ssrc[i + 8 + e], s3 = ssrc[i + 12 + e];
            uint2 u0 = *(const uint2*)&t1b8[(size_t)s0 * 128 + q * 8];
            uint2 u1 = *(const uint2*)&t1b8[(size_t)s1 * 128 + q * 8];
            uint2 u2 = *(const uint2*)&t1b8[(size_t)s2 * 128 + q * 8];
            uint2 u3 = *(const uint2*)&t1b8[(size_t)s3 * 128 + q * 8];
#pragma unroll
            for (int m = 0; m < 4; ++m) {
                uint2 u = (m == 0) ? u0 : (m == 1) ? u1 : (m == 2) ? u2 : u3;
                v2f f0 = __builtin_amdgcn_cvt_pk_f32_fp8((int)u.x, false);
                v2f f1 = __builtin_amdgcn_cvt_pk_f32_fp8((int)u.x, true);
                v2f f2 = __builtin_amdgcn_cvt_pk_f32_fp8((int)u.y, false);
                v2f f3 = __builtin_amdgcn_cvt_pk_f32_fp8((int)u.y, true);
                acc[0] += f0[0]; acc[1] += f0[1]; acc[2] += f1[0]; acc[3] += f1[1];
                acc[4] += f2[0]; acc[5] += f2[1]; acc[6] += f3[0]; acc[7] += f3[1];
            }
        }
        for (; i + 4 <= hi; i += 4) {
            int s = ssrc[i + e];
            uint2 u = *(const uint2*)&t1b8[(size_t)s * 128 + q * 8];
            v2f f0 = __builtin_amdgcn_cvt_pk_f32_fp8((int)u.x, false);
            v2f f1 = __builtin_amdgcn_cvt_pk_f32_fp8((int)u.x, true);
            v2f f2 = __builtin_amdgcn_cvt_pk_f32_fp8((int)u.y, false);
            v2f f3 = __builtin_amdgcn_cvt_pk_f32_fp8((int)u.y, true);
            acc[0] += f0[0]; acc[1] += f0[1]; acc[2] += f1[0]; acc[3] += f1[1];
            acc[4] += f2[0]; acc[5] += f2[1]; acc[6] += f3[0]; acc[7] += f3[1];
        }
        if (e < hi - i) {
            int s = ssrc[i + e];
            uint2 u = *(const uint2*)&t1b8[(size_t)s * 128 + q * 8];
            v2f f0 = __builtin_amdgcn_cvt_pk_f32_fp8((int)u.x, false);
            v2f f1 = __builtin_amdgcn_cvt_pk_f32_fp8((int)u.x, true);
            v2f f2 = __builtin_amdgcn_cvt_pk_f32_fp8((int)u.y, false);
            v2f f3 = __builtin_amdgcn_cvt_pk_f32_fp8((int)u.y, true);
            acc[0] += f0[0]; acc[1] += f0[1]; acc[2] += f1[0]; acc[3] += f1[1];
            acc[4] += f2[0]; acc[5] += f2[1]; acc[6] += f3[0]; acc[7] += f3[1];
        }
#pragma unroll
        for (int j = 0; j < 8; ++j) {
            acc[j] += __shfl_xor(acc[j], 16);
            acc[j] += __shfl_xor(acc[j], 32);
        }
        if (e == 0) {
            float c = (float)(hi - lo);
            if (c < 1.f) c = 1.f;
            float inv = 1.0f / c;
            float4 bA = *(const float4*)&b1[q * 8];
            float4 bB = *(const float4*)&b1[q * 8 + 4];
            uint4 ur = *(const uint4*)&r1b[(size_t)n * 128 + q * 8];
            float v0 = acc[0] * inv + bA.x + bf2f_lo(ur.x);
            float v1 = acc[1] * inv + bA.y + bf2f_hi(ur.x);
            float v2 = acc[2] * inv + bA.z + bf2f_lo(ur.y);
            float v3 = acc[3] * inv + bA.w + bf2f_hi(ur.y);
            float v4 = acc[4] * inv + bB.x + bf2f_lo(ur.z);
            float v5 = acc[5] * inv + bB.y + bf2f_hi(ur.z);
            float v6 = acc[6] * inv + bB.z + bf2f_lo(ur.w);
            float v7 = acc[7] * inv + bB.w + bf2f_hi(ur.w);
            uint4 pw = { pk2(v0, v1), pk2(v2, v3), pk2(v4, v5), pk2(v6, v7) };
            *(uint4*)&hpreb[(size_t)n * 128 + q * 8] = pw;
            sa[0] += v0; sa[1] += v1; sa[2] += v2; sa[3] += v3;
            sa[4] += v4; sa[5] += v5; sa[6] += v6; sa[7] += v7;
            sq[0] += v0 * v0; sq[1] += v1 * v1; sq[2] += v2 * v2; sq[3] += v3 * v3;
            sq[4] += v4 * v4; sq[5] += v5 * v5; sq[6] += v6 * v6; sq[7] += v7 * v7;
        }
    }

    __shared__ float red[2][4][128];
    if (e == 0) {
#pragma unroll
        for (int j = 0; j < 8; ++j) {
            red[0][wv][q * 8 + j] = sa[j];
            red[1][wv][q * 8 + j] = sq[j];
        }
    }
    __syncthreads();
    int t = threadIdx.x;
    if (t < 128) {
        atomicAdd(&bn[t], red[0][0][t] + red[0][1][t] + red[0][2][t] + red[0][3][t]);
    } else {
        int f = t - 128;
        atomicAdd(&bn[128 + f], red[1][0][f] + red[1][1][f] + red[1][2][f] + red[1][3][f]);
    }
}

// ---------- layer 2 MFMA GEMM with fused BN-finalize + BN+ReLU ----------
__global__ __launch_bounds__(256) void k_gemm2m(const unsigned short* __restrict__ hpreb,
                                                const float* __restrict__ bnp,
                                                const float* __restrict__ gamma, const float* __restrict__ beta,
                                                const float* __restrict__ Wl, const float* __restrict__ Wr,
                                                unsigned short* __restrict__ t2b,
                                                unsigned short* __restrict__ r2b) {
    __shared__ unsigned short As[32 * 128];
    __shared__ unsigned short Bs[128 * 128];
    __shared__ float scs[128], shs[128];
    const int t = threadIdx.x;
    const size_t n0 = (size_t)blockIdx.x * 32;

    if (t < 128) {
        float mean = bnp[t] * (1.0f / N_NODES);
        float var  = bnp[128 + t] * (1.0f / N_NODES) - mean * mean;
        float sc = gamma[t] * rsqrtf(var + EPSV);
        scs[t] = sc;
        shs[t] = beta[t] - mean * sc;
    }
    __syncthreads();

    {
        const int r = t >> 3, s = t & 7;
        const unsigned short* hr = hpreb + (n0 + r) * 128 + s * 16;
        uint4 h0 = *(const uint4*)(hr + 0);
        uint4 h1 = *(const uint4*)(hr + 8);
        unsigned int hv[8] = { h0.x, h0.y, h0.z, h0.w, h1.x, h1.y, h1.z, h1.w };
        float v[16];
#pragma unroll
        for (int j = 0; j < 8; ++j) {
            v[2 * j]     = bf2f_lo(hv[j]);
            v[2 * j + 1] = bf2f_hi(hv[j]);
        }
#pragma unroll
        for (int j = 0; j < 16; ++j) {
            int f = s * 16 + j;
            float val = fmaf(scs[f], v[j], shs[f]);
            v[j] = val > 0.f ? val : 0.f;
        }
        uint4 p0 = { pk2(v[0], v[1]), pk2(v[2], v[3]), pk2(v[4], v[5]), pk2(v[6], v[7]) };
        uint4 p1 = { pk2(v[8], v[9]), pk2(v[10], v[11]), pk2(v[12], v[13]), pk2(v[14], v[15]) };
        int sw = (r & 7) << 3;
        *(uint4*)&As[(r * 128 + s * 16 + 0) ^ sw] = p0;
        *(uint4*)&As[(r * 128 + s * 16 + 8) ^ sw] = p1;
    }
    {
        const int n = t & 127, kh = t >> 7;
        const float* wc = (n < 64) ? (Wl + n) : (Wr + (n - 64));
        int sw = (n & 7) << 3;
#pragma unroll
        for (int k = kh * 64; k < kh * 64 + 64; k += 8) {
            float a0 = wc[(k + 0) * 64], a1 = wc[(k + 1) * 64];
            float a2 = wc[(k + 2) * 64], a3 = wc[(k + 3) * 64];
            float a4 = wc[(k + 4) * 64], a5 = wc[(k + 5) * 64];
            float a6 = wc[(k + 6) * 64], a7 = wc[(k + 7) * 64];
            uint4 p = { pk2(a0, a1), pk2(a2, a3), pk2(a4, a5), pk2(a6, a7) };
            *(uint4*)&Bs[(n * 128 + k) ^ sw] = p;
        }
    }
    __syncthreads();

    const int w = t >> 6, l = t & 63;
    const int lr = l & 15, lg = l >> 4;
    v4f acc00 = {0.f, 0.f, 0.f, 0.f}, acc01 = acc00, acc10 = acc00, acc11 = acc00;
    const int swA = (lr & 7) << 3;
    const int nA = w * 32 + lr;
    const int swB = (nA & 7) << 3;
#pragma unroll
    for (int ks = 0; ks < 4; ++ks) {
        const int ka = ks * 32 + lg * 8;
        v8s a0 = *(const v8s*)&As[(lr * 128 + ka) ^ swA];
        v8s a1 = *(const v8s*)&As[((16 + lr) * 128 + ka) ^ swA];
        v8s b0 = *(const v8s*)&Bs[(nA * 128 + ka) ^ swB];
        v8s b1 = *(const v8s*)&Bs[((nA + 16) * 128 + ka) ^ swB];
        acc00 = __builtin_amdgcn_mfma_f32_16x16x32_bf16(a0, b0, acc00, 0, 0, 0);
        acc01 = __builtin_amdgcn_mfma_f32_16x16x32_bf16(a0, b1, acc01, 0, 0, 0);
        acc10 = __builtin_amdgcn_mfma_f32_16x16x32_bf16(a1, b0, acc10, 0, 0, 0);
        acc11 = __builtin_amdgcn_mfma_f32_16x16x32_bf16(a1, b1, acc11, 0, 0, 0);
    }
    unsigned short* __restrict__ ob = (w < 2) ? t2b : r2b;
    const int col0 = (w < 2) ? (w * 32 + lr) : ((w - 2) * 32 + lr);
#pragma unroll
    for (int reg = 0; reg < 4; ++reg) {
        size_t row0 = n0 + lg * 4 + reg;
        size_t row1 = row0 + 16;
        ob[row0 * 64 + col0]      = f2bf(acc00[reg]);
        ob[row0 * 64 + col0 + 16] = f2bf(acc01[reg]);
        ob[row1 * 64 + col0]      = f2bf(acc10[reg]);
        ob[row1 * 64 + col0 + 16] = f2bf(acc11[reg]);
    }
}

// ---------- layer 2 aggregate: 4 edges per wave-load (4 bf16/lane, 16 lanes/row) ----------
__global__ __launch_bounds__(256) void k_agg2(const unsigned short* __restrict__ t2b,
                                              const unsigned short* __restrict__ r2b,
                                              const int* __restrict__ rowptr,
                                              const int* __restrict__ ssrc, const float* __restrict__ b2,
                                              float* __restrict__ out) {
    const int wv = threadIdx.x >> 6;
    const int l  = threadIdx.x & 63;
    const int e  = l >> 4;
    const int q  = l & 15;
    const int nbase = blockIdx.x * 16;

    for (int r = wv; r < 16; r += 4) {
        const int n = nbase + r;
        const int lo = rowptr[n], hi = rowptr[n + 1];
        float a0 = 0.f, a1 = 0.f, a2 = 0.f, a3 = 0.f;
        int i = lo;
        for (; i + 16 <= hi; i += 16) {
            int s0 = ssrc[i + e], s1 = ssrc[i + 4 + e], s2 = ssrc[i + 8 + e], s3 = ssrc[i + 12 + e];
            uint2 u0 = *(const uint2*)&t2b[(size_t)s0 * 64 + q * 4];
            uint2 u1 = *(const uint2*)&t2b[(size_t)s1 * 64 + q * 4];
            uint2 u2 = *(const uint2*)&t2b[(size_t)s2 * 64 + q * 4];
            uint2 u3 = *(const uint2*)&t2b[(size_t)s3 * 64 + q * 4];
            a0 += bf2f_lo(u0.x) + bf2f_lo(u1.x) + bf2f_lo(u2.x) + bf2f_lo(u3.x);
            a1 += bf2f_hi(u0.x) + bf2f_hi(u1.x) + bf2f_hi(u2.x) + bf2f_hi(u3.x);
            a2 += bf2f_lo(u0.y) + bf2f_lo(u1.y) + bf2f_lo(u2.y) + bf2f_lo(u3.y);
            a3 += bf2f_hi(u0.y) + bf2f_hi(u1.y) + bf2f_hi(u2.y) + bf2f_hi(u3.y);
        }
        for (; i + 4 <= hi; i += 4) {
            int s = ssrc[i + e];
            uint2 u = *(const uint2*)&t2b[(size_t)s * 64 + q * 4];
            a0 += bf2f_lo(u.x); a1 += bf2f_hi(u.x);
            a2 += bf2f_lo(u.y); a3 += bf2f_hi(u.y);
        }
        if (e < hi - i) {
            int s = ssrc[i + e];
            uint2 u = *(const uint2*)&t2b[(size_t)s * 64 + q * 4];
            a0 += bf2f_lo(u.x); a1 += bf2f_hi(u.x);
            a2 += bf2f_lo(u.y); a3 += bf2f_hi(u.y);
        }
        a0 += __shfl_xor(a0, 16); a0 += __shfl_xor(a0, 32);
        a1 += __shfl_xor(a1, 16); a1 += __shfl_xor(a1, 32);
        a2 += __shfl_xor(a2, 16); a2 += __shfl_xor(a2, 32);
        a3 += __shfl_xor(a3, 16); a3 += __shfl_xor(a3, 32);
        if (e == 0) {
            float c = (float)(hi - lo);
            if (c < 1.f) c = 1.f;
            float inv = 1.0f / c;
            float4 bias = *(const float4*)&b2[q * 4];
            uint2 ur = *(const uint2*)&r2b[(size_t)n * 64 + q * 4];
            float4 o = { a0 * inv + bias.x + bf2f_lo(ur.x),
                         a1 * inv + bias.y + bf2f_hi(ur.x),
                         a2 * inv + bias.z + bf2f_lo(ur.y),
                         a3 * inv + bias.w + bf2f_hi(ur.y) };
            *(float4*)&out[(size_t)n * 64 + q * 4] = o;
        }
    }
}

extern "C" void kernel_launch(void* const* d_in, const int* in_sizes, int n_in,
                              void* d_out, int out_size, void* d_ws, size_t ws_size,
                              hipStream_t stream) {
    const float* x      = (const float*)d_in[0];
    const int*   ei     = (const int*)d_in[1];
    const float* Wl1    = (const float*)d_in[2];
    const float* b1     = (const float*)d_in[3];
    const float* Wr1    = (const float*)d_in[4];
    const float* gamma1 = (const float*)d_in[5];
    const float* beta1  = (const float*)d_in[6];
    const float* Wl2    = (const float*)d_in[7];
    const float* b2     = (const float*)d_in[8];
    const float* Wr2    = (const float*)d_in[9];
    float* out = (float*)d_out;

    char* ws = (char*)d_ws;
    int*                rowptr = (int*)(ws + OFF_ROWPTR);
    int*                bc     = (int*)(ws + OFF_BC);
    int*                gbase  = (int*)(ws + OFF_GB);
    float*              bn     = (float*)(ws + OFF_BN);
    int*                ssrc   = (int*)(ws + OFF_SRC);
    unsigned char*      t1b8   = (unsigned char*)(ws + OFF_T1B);
    unsigned short*     r1b    = (unsigned short*)(ws + OFF_R1B);
    unsigned short*     hpreb  = (unsigned short*)(ws + OFF_HPRE);
    unsigned short*     t2b    = (unsigned short*)(ws + OFF_T1B);
    unsigned short*     r2b    = r1b;
    unsigned long long* tmp    = (unsigned long long*)(ws + OFF_TMP);

    const int* esrc = ei;
    const int* edst = ei + N_EDGES;

    hipMemsetAsync(bc, 0, NBUK * 16 * sizeof(int), stream);
    hipMemsetAsync(bn, 0, 256 * sizeof(float), stream);

    k_gemm1h<<<HIST_NBLK + 2 * GEMM_MBLK, 256, 0, stream>>>(x, Wl1, Wr1, t1b8, r1b, edst, bc);
    k_scan98<<<1, 128, 0, stream>>>(bc, gbase, rowptr);
    k_partA<<<PA_NBLK, 256, 0, stream>>>(esrc, edst, bc, tmp);
    k_partB<<<NBUK, 1024, 0, stream>>>(tmp, gbase, rowptr, ssrc);

    k_agg1<<<N_NODES / 32, 256, 0, stream>>>(t1b8, r1b, rowptr, ssrc, b1, hpreb, bn);
    k_gemm2m<<<GEMM_MBLK, 256, 0, stream>>>(hpreb, bn, gamma1, beta1, Wl2, Wr2, t2b, r2b);
    k_agg2<<<N_NODES / 16, 256, 0, stream>>>(t2b, r2b, rowptr, ssrc, b2, out);
}